// Round 2
// baseline (597.024 us; speedup 1.0000x reference)
//
#include <hip/hip_runtime.h>

#define NN 2048
#define DD 256
#define HH 4
#define ECAP 128
#define NBLK 512

typedef unsigned short ushort_t;
typedef __attribute__((ext_vector_type(4))) unsigned short us4;
typedef __attribute__((ext_vector_type(8))) unsigned short us8;
typedef __attribute__((ext_vector_type(8))) short s8;
typedef __attribute__((ext_vector_type(4))) float f4;

__device__ __forceinline__ ushort_t f2b(float f) {   // fp32 -> bf16 bits, RNE
    unsigned int u = __float_as_uint(f);
    return (ushort_t)((u + 0x7fffu + ((u >> 16) & 1u)) >> 16);
}
__device__ __forceinline__ float b2f(ushort_t b) {
    return __uint_as_float(((unsigned int)b) << 16);
}
__device__ __forceinline__ void gl_lds16(const void* g, void* l) {
    __builtin_amdgcn_global_load_lds(
        (const __attribute__((address_space(1))) void*)g,
        (__attribute__((address_space(3))) void*)l, 16, 0, 0);
}

// Device-scope grid barrier (one counter per sync point, zeroed host-side).
// Writer: threadfence (agent release -> buffer_wbl2) then arrive.
// Reader: spin on acquire load, then threadfence (buffer_inv) so later loads
// see remote XCDs' writes. Co-residency guaranteed: NBLK=512 = 2 blocks/CU
// with __launch_bounds__(256,2) (VGPR<=256) and 32KB LDS (<=4/CU).
__device__ __forceinline__ void gsync(int* bar) {
    __threadfence();
    __syncthreads();
    if (threadIdx.x == 0) {
        __hip_atomic_fetch_add(bar, 1, __ATOMIC_ACQ_REL, __HIP_MEMORY_SCOPE_AGENT);
        while (__hip_atomic_load(bar, __ATOMIC_ACQUIRE, __HIP_MEMORY_SCOPE_AGENT) < NBLK)
            __builtin_amdgcn_s_sleep(1);
    }
    __syncthreads();
    __threadfence();
}

// ---------------------------------------------------------------------------
// bf16 gemm core, double-buffered gl_lds staging, XOR-swizzled [64][64] x2.
// ---------------------------------------------------------------------------
__device__ __forceinline__ void gemm_core_db(
    const ushort_t* __restrict__ A, int lda, const ushort_t* __restrict__ B, int ldb,
    int r0, int c0, int K, ushort_t (*as)[64], ushort_t (*bs)[64], f4 acc[2][2])
{
    const int t = threadIdx.x;
    const int wave = t >> 6, lane = t & 63;
    const int wm = (wave & 1) * 32, wn = (wave >> 1) * 32;
    const int fm = lane & 15, fq = lane >> 4;

    const int m0q0 = wave * 16 + (lane >> 3);
    const int m0q1 = m0q0 + 8;
    const int cs0 = ((lane & 7) ^ (m0q0 & 7)) * 8;
    const int cs1 = ((lane & 7) ^ (m0q1 & 7)) * 8;
    const ushort_t* ga0 = A + (size_t)(r0 + m0q0) * lda + cs0;
    const ushort_t* ga1 = A + (size_t)(r0 + m0q1) * lda + cs1;
    const ushort_t* gb0 = B + (size_t)(c0 + m0q0) * ldb + cs0;
    const ushort_t* gb1 = B + (size_t)(c0 + m0q1) * ldb + cs1;
    const int ra0 = wm + fm, ra1 = wm + 16 + fm;
    const int rb0 = wn + fm, rb1 = wn + 16 + fm;

    gl_lds16(ga0, &as[wave * 16][0]);
    gl_lds16(ga1, &as[wave * 16 + 8][0]);
    gl_lds16(gb0, &bs[wave * 16][0]);
    gl_lds16(gb1, &bs[wave * 16 + 8][0]);
    __syncthreads();

    int buf = 0;
    for (int k0 = 0; k0 < K; k0 += 64) {
        const int nb = buf ^ 64;
        if (k0 + 64 < K) {
            gl_lds16(ga0 + k0 + 64, &as[nb + wave * 16][0]);
            gl_lds16(ga1 + k0 + 64, &as[nb + wave * 16 + 8][0]);
            gl_lds16(gb0 + k0 + 64, &bs[nb + wave * 16][0]);
            gl_lds16(gb1 + k0 + 64, &bs[nb + wave * 16 + 8][0]);
        }
        #pragma unroll
        for (int kk = 0; kk < 2; ++kk) {
            const int cc = kk * 4 + fq;
            const s8 a0 = *(const s8*)&as[buf + ra0][(cc ^ (ra0 & 7)) * 8];
            const s8 a1 = *(const s8*)&as[buf + ra1][(cc ^ (ra1 & 7)) * 8];
            const s8 b0 = *(const s8*)&bs[buf + rb0][(cc ^ (rb0 & 7)) * 8];
            const s8 b1 = *(const s8*)&bs[buf + rb1][(cc ^ (rb1 & 7)) * 8];
            acc[0][0] = __builtin_amdgcn_mfma_f32_16x16x32_bf16(a0, b0, acc[0][0], 0, 0, 0);
            acc[0][1] = __builtin_amdgcn_mfma_f32_16x16x32_bf16(a0, b1, acc[0][1], 0, 0, 0);
            acc[1][0] = __builtin_amdgcn_mfma_f32_16x16x32_bf16(a1, b0, acc[1][0], 0, 0, 0);
            acc[1][1] = __builtin_amdgcn_mfma_f32_16x16x32_bf16(a1, b1, acc[1][1], 0, 0, 0);
        }
        __syncthreads();
        buf = nb;
    }
}

__device__ __forceinline__ us8 cvt8(float4 a, float4 b) {
    us8 o;
    o[0] = f2b(a.x); o[1] = f2b(a.y); o[2] = f2b(a.z); o[3] = f2b(a.w);
    o[4] = f2b(b.x); o[5] = f2b(b.y); o[6] = f2b(b.z); o[7] = f2b(b.w);
    return o;
}

// fp32-input gemm core, reg-prefetch (issue-early/write-late), same numerics.
__device__ __forceinline__ void gemm_core_f32(
    const float* __restrict__ A, int lda, const float* __restrict__ B, int ldb,
    int r0, int c0, int K, ushort_t (*as)[64], ushort_t (*bs)[64], f4 acc[2][2])
{
    const int t = threadIdx.x;
    const int wave = t >> 6, lane = t & 63;
    const int wm = (wave & 1) * 32, wn = (wave >> 1) * 32;
    const int fm = lane & 15, fq = lane >> 4;

    const int m1 = wave * 16 + (lane >> 3);
    const int m2 = m1 + 8;
    const int g1 = ((lane & 7) ^ (m1 & 7)) * 8;
    const int g2 = ((lane & 7) ^ (m2 & 7)) * 8;
    const int cl = (lane & 7) * 8;
    const int ra0 = wm + fm, ra1 = wm + 16 + fm;
    const int rb0 = wn + fm, rb1 = wn + 16 + fm;

    const float* pa1 = A + (size_t)(r0 + m1) * lda + g1;
    const float* pa2 = A + (size_t)(r0 + m2) * lda + g2;
    const float* pb1 = B + (size_t)(c0 + m1) * ldb + g1;
    const float* pb2 = B + (size_t)(c0 + m2) * ldb + g2;

    float4 aa0 = *(const float4*)(pa1);
    float4 aa1 = *(const float4*)(pa1 + 4);
    float4 ab0 = *(const float4*)(pa2);
    float4 ab1 = *(const float4*)(pa2 + 4);
    float4 ba0 = *(const float4*)(pb1);
    float4 ba1 = *(const float4*)(pb1 + 4);
    float4 bb0 = *(const float4*)(pb2);
    float4 bb1 = *(const float4*)(pb2 + 4);

    for (int k0 = 0; k0 < K; k0 += 64) {
        __syncthreads();
        *(us8*)&as[m1][cl] = cvt8(aa0, aa1);
        *(us8*)&as[m2][cl] = cvt8(ab0, ab1);
        *(us8*)&bs[m1][cl] = cvt8(ba0, ba1);
        *(us8*)&bs[m2][cl] = cvt8(bb0, bb1);
        __syncthreads();
        if (k0 + 64 < K) {
            aa0 = *(const float4*)(pa1 + k0 + 64);
            aa1 = *(const float4*)(pa1 + k0 + 68);
            ab0 = *(const float4*)(pa2 + k0 + 64);
            ab1 = *(const float4*)(pa2 + k0 + 68);
            ba0 = *(const float4*)(pb1 + k0 + 64);
            ba1 = *(const float4*)(pb1 + k0 + 68);
            bb0 = *(const float4*)(pb2 + k0 + 64);
            bb1 = *(const float4*)(pb2 + k0 + 68);
        }
        #pragma unroll
        for (int kk = 0; kk < 2; ++kk) {
            const int cc = kk * 4 + fq;
            const s8 a0 = *(const s8*)&as[ra0][(cc ^ (ra0 & 7)) * 8];
            const s8 a1 = *(const s8*)&as[ra1][(cc ^ (ra1 & 7)) * 8];
            const s8 b0 = *(const s8*)&bs[rb0][(cc ^ (rb0 & 7)) * 8];
            const s8 b1 = *(const s8*)&bs[rb1][(cc ^ (rb1 & 7)) * 8];
            acc[0][0] = __builtin_amdgcn_mfma_f32_16x16x32_bf16(a0, b0, acc[0][0], 0, 0, 0);
            acc[0][1] = __builtin_amdgcn_mfma_f32_16x16x32_bf16(a0, b1, acc[0][1], 0, 0, 0);
            acc[1][0] = __builtin_amdgcn_mfma_f32_16x16x32_bf16(a1, b0, acc[1][0], 0, 0, 0);
            acc[1][1] = __builtin_amdgcn_mfma_f32_16x16x32_bf16(a1, b1, acc[1][1], 0, 0, 0);
        }
    }
}

#define E_SC  256
#define E_AP  384
#define E_WI  768
#define E_NB  1408

// ---------------------------------------------------------------------------
// Persistent mega-kernel: StageA (scan/proj/wihcvt/gemm1) | gsync |
// StageB attn (1 (i,l) per wave) | gsync | StageC gemm2 | gsync | StageD gates.
// All stage arithmetic orders identical to the 4-kernel version.
// ---------------------------------------------------------------------------
__global__ __launch_bounds__(256, 2) void mega_kernel(
    const float* __restrict__ x,
    const float* __restrict__ adj0, const float* __restrict__ adj1,
    const float* __restrict__ w0, const float* __restrict__ w1,
    const float* __restrict__ Wm0, const float* __restrict__ Wm1,
    const float* __restrict__ whh, const float* __restrict__ wih,
    const float* __restrict__ Wa0, const float* __restrict__ Wa1,
    const float* __restrict__ bm0, const float* __restrict__ bm1,
    const float* __restrict__ bhh,
    const float* __restrict__ ba0, const float* __restrict__ ba1,
    const float* __restrict__ bih,
    const float* __restrict__ lng, const float* __restrict__ lnb,
    int* __restrict__ cnt, int* __restrict__ ej,
    ushort_t* __restrict__ wihb,
    float* __restrict__ acur, float* __restrict__ anb,
    ushort_t* __restrict__ msgb, ushort_t* __restrict__ mcatb,
    float* __restrict__ gh, float* __restrict__ gi,
    float* __restrict__ out, int* __restrict__ bar)
{
    __shared__ __align__(16) char smem[32768];
    const int rb = blockIdx.x, t = threadIdx.x;

    // ======================= Stage A =======================
    for (int vb = rb; vb < E_NB; vb += NBLK) {
        if (vb < E_SC) {                       // ---- adj-only edge scan ----
            const int l = vb & 1, chunk = vb >> 1;
            const int i0 = chunk * 16;
            const float* adj = l ? adj1 : adj0;
            int* lcnt = (int*)smem;
            if (t < 16) lcnt[t] = 0;
            __syncthreads();
            const int rowLane = t >> 2, q = t & 3;
            for (int r0r = 0; r0r < NN; r0r += 512) {
                float4 a[8];
                #pragma unroll
                for (int it = 0; it < 8; ++it) {
                    const int j = r0r + it * 64 + rowLane;
                    a[it] = *(const float4*)(adj + (size_t)j * NN + i0 + q * 4);
                }
                #pragma unroll
                for (int it = 0; it < 8; ++it) {
                    const int j = r0r + it * 64 + rowLane;
                    const float av[4] = {a[it].x, a[it].y, a[it].z, a[it].w};
                    #pragma unroll
                    for (int u = 0; u < 4; ++u) {
                        if (av[u] != 0.f) {
                            const int li = q * 4 + u;
                            const int slot = atomicAdd(&lcnt[li], 1);
                            if (slot < ECAP)
                                ej[((size_t)l * NN + i0 + li) * ECAP + slot] = j;
                        }
                    }
                }
            }
            __syncthreads();
            if (t < 16) cnt[l * NN + i0 + t] = min(lcnt[t], ECAP);
        } else if (vb < E_AP) {                // ---- attn_proj ----
            float* sh = (float*)smem;          // [16][257]
            const int i0 = (vb - E_SC) * 16;
            for (int rr = 0; rr < 16; ++rr)
                sh[rr * 257 + t] = x[(size_t)(i0 + rr) * DD + t];
            __syncthreads();
            const int r = t >> 4, idx = t & 15;
            const int l = idx >> 3, isnb = (idx >> 2) & 1, h = idx & 3;
            const float* wrow = (l ? Wa1 : Wa0) + h * (2 * DD) + isnb * DD;
            float acc = 0.f;
            for (int k = 0; k < DD; ++k) acc = fmaf(sh[r * 257 + k], wrow[k], acc);
            float* dst = isnb ? anb : acur;
            dst[((size_t)l * NN + i0 + r) * HH + h] = acc;
        } else if (vb < E_WI) {                // ---- wih -> bf16 ----
            const int id = (vb - E_AP) * 1024 + t * 4;
            const float4 v = *(const float4*)(wih + id);
            us4 o; o.x = f2b(v.x); o.y = f2b(v.y); o.z = f2b(v.z); o.w = f2b(v.w);
            *(us4*)(wihb + id) = o;
        } else {                               // ---- gemm1 tile (fp32 in) ----
            ushort_t (*as)[64] = (ushort_t(*)[64])smem;
            ushort_t (*bs)[64] = (ushort_t(*)[64])(smem + 8192);
            const int wave = t >> 6, lane = t & 63;
            const int wm = (wave & 1) * 32, wn = (wave >> 1) * 32;
            const int fm = lane & 15, fq = lane >> 4;
            const int idx = vb - E_WI;
            const int c0 = (idx % 20) * 64, r0 = (idx / 20) * 64;
            const float* Bsrc = (c0 < 256) ? Wm0 + (size_t)c0 * DD
                              : (c0 < 512) ? Wm1 + (size_t)(c0 - 256) * DD
                                           : whh + (size_t)(c0 - 512) * DD;
            f4 acc[2][2] = {};
            gemm_core_f32(x, DD, Bsrc, DD, r0, 0, DD, as, bs, acc);
            #pragma unroll
            for (int ni = 0; ni < 2; ++ni) {
                const int col = c0 + wn + ni * 16 + fm;
                const float bv = (col < 256) ? bm0[col]
                               : (col < 512) ? bm1[col - 256]
                                             : bhh[col - 512];
                #pragma unroll
                for (int mi = 0; mi < 2; ++mi) {
                    #pragma unroll
                    for (int r = 0; r < 4; ++r) {
                        const int row = r0 + wm + mi * 16 + fq * 4 + r;
                        const float v = acc[mi][ni][r] + bv;
                        if (col < 512) msgb[(size_t)row * 512 + col] = f2b(v);
                        else           gh[(size_t)row * 768 + col - 512] = v;
                    }
                }
            }
        }
        __syncthreads();                       // smem reuse fence between vbs
    }
    gsync(bar + 0);

    // ======================= Stage B: attn =======================
    // One (i,l) per wave; softmax in registers (same slot layout & fold order
    // as the block version: lane covers slots lane and lane+64). Probabilities
    // stashed in per-wave LDS for the aggregation broadcast.
    {
        const int wave = t >> 6, lane = t & 63;
        float (*esw)[ECAP] = (float(*)[ECAP])smem + wave * HH;   // 2KB/wave
        int* ejs = (int*)(smem + 8192) + wave * ECAP;            // 512B/wave
        for (int it = 0; it < 2; ++it) {
            const int pair = it * 2048 + rb * 4 + wave;
            const int i = pair & (NN - 1), l = pair >> 11;
            const int ne = min(max(cnt[l * NN + i], 0), ECAP);
            const float* ba = l ? ba1 : ba0;
            const float* w  = l ? w1 : w0;
            const size_t ebase = ((size_t)l * NN + i) * ECAP;
            float acv[4];
            #pragma unroll
            for (int h = 0; h < HH; ++h)
                acv[h] = acur[((size_t)l * NN + i) * HH + h];

            float s0[HH], s1[HH];
            int j0 = 0, j1 = 0;
            if (lane < ne) {
                j0 = ej[ebase + lane];
                const float wv = w[(size_t)j0 * NN + i];
                const float4 av = *(const float4*)(anb + ((size_t)l * NN + j0) * HH);
                const float sv[4] = {av.x, av.y, av.z, av.w};
                #pragma unroll
                for (int h = 0; h < HH; ++h) {
                    float s = sv[h] + acv[h] + ba[h];
                    s = (s > 0.f) ? s : 0.2f * s;
                    s0[h] = s * wv;
                }
            } else {
                #pragma unroll
                for (int h = 0; h < HH; ++h) s0[h] = -1e30f;
            }
            if (lane + 64 < ne) {
                j1 = ej[ebase + lane + 64];
                const float wv = w[(size_t)j1 * NN + i];
                const float4 av = *(const float4*)(anb + ((size_t)l * NN + j1) * HH);
                const float sv[4] = {av.x, av.y, av.z, av.w};
                #pragma unroll
                for (int h = 0; h < HH; ++h) {
                    float s = sv[h] + acv[h] + ba[h];
                    s = (s > 0.f) ? s : 0.2f * s;
                    s1[h] = s * wv;
                }
            } else {
                #pragma unroll
                for (int h = 0; h < HH; ++h) s1[h] = -1e30f;
            }
            #pragma unroll
            for (int h = 0; h < HH; ++h) {
                float m = fmaxf(s0[h], s1[h]);
                #pragma unroll
                for (int off = 32; off; off >>= 1) m = fmaxf(m, __shfl_xor(m, off));
                const float p0 = expf(s0[h] - m), p1 = expf(s1[h] - m);
                float sum = p0 + p1;
                #pragma unroll
                for (int off = 32; off; off >>= 1) sum += __shfl_xor(sum, off);
                const float inv = (ne > 0) ? 1.f / sum : 0.f;
                esw[h][lane] = p0 * inv;
                esw[h][lane + 64] = p1 * inv;
            }
            ejs[lane] = j0;
            ejs[lane + 64] = j1;
            // aggregation: lane owns 4 consecutive cols; same-wave LDS RAW is
            // ordered by hardware + compiler lgkmcnt (no barrier needed).
            const int h = lane >> 4;
            const size_t obase = (size_t)(l * DD) + lane * 4;
            float a0 = 0.f, a1 = 0.f, a2 = 0.f, a3 = 0.f;
            int e = 0;
            for (; e + 8 <= ne; e += 8) {
                int jv[8]; float pv[8]; us4 mv[8];
                #pragma unroll
                for (int u = 0; u < 8; ++u) { jv[u] = ejs[e + u]; pv[u] = esw[h][e + u]; }
                #pragma unroll
                for (int u = 0; u < 8; ++u)
                    mv[u] = *(const us4*)&msgb[(size_t)jv[u] * 512 + obase];
                #pragma unroll
                for (int u = 0; u < 8; ++u) {
                    a0 = fmaf(pv[u], b2f(mv[u].x), a0);
                    a1 = fmaf(pv[u], b2f(mv[u].y), a1);
                    a2 = fmaf(pv[u], b2f(mv[u].z), a2);
                    a3 = fmaf(pv[u], b2f(mv[u].w), a3);
                }
            }
            for (; e < ne; ++e) {
                const us4 mv = *(const us4*)&msgb[(size_t)ejs[e] * 512 + obase];
                const float pe = esw[h][e];
                a0 = fmaf(pe, b2f(mv.x), a0);
                a1 = fmaf(pe, b2f(mv.y), a1);
                a2 = fmaf(pe, b2f(mv.z), a2);
                a3 = fmaf(pe, b2f(mv.w), a3);
            }
            us4 o; o.x = f2b(a0); o.y = f2b(a1); o.z = f2b(a2); o.w = f2b(a3);
            *(us4*)&mcatb[(size_t)i * (2 * DD) + obase] = o;
        }
    }
    gsync(bar + 1);

    // ======================= Stage C: gemm2 =======================
    if (rb < 384) {
        ushort_t (*as)[64] = (ushort_t(*)[64])smem;            // 2x64 rows
        ushort_t (*bs)[64] = (ushort_t(*)[64])(smem + 16384);
        const int wave = t >> 6, lane = t & 63;
        const int wm = (wave & 1) * 32, wn = (wave >> 1) * 32;
        const int fm = lane & 15, fq = lane >> 4;
        const int c0 = (rb % 12) * 64, r0 = (rb / 12) * 64;
        f4 acc[2][2] = {};
        gemm_core_db(mcatb, 512, wihb, 512, r0, c0, 512, as, bs, acc);
        #pragma unroll
        for (int ni = 0; ni < 2; ++ni) {
            const int col = c0 + wn + ni * 16 + fm;
            const float bv = bih[col];
            #pragma unroll
            for (int mi = 0; mi < 2; ++mi)
                #pragma unroll
                for (int r = 0; r < 4; ++r)
                    gi[(size_t)(r0 + wm + mi * 16 + fq * 4 + r) * 768 + col] =
                        acc[mi][ni][r] + bv;
        }
    }
    gsync(bar + 2);

    // ======================= Stage D: gates + LN =======================
    {
        const int lane = t & 63, wv = t >> 6;
        const int row = rb * 4 + wv;
        const size_t b768 = (size_t)row * 768;
        const int c = lane * 4;
        const f4 gir = *(const f4*)(gi + b768 + c);
        const f4 giz = *(const f4*)(gi + b768 + 256 + c);
        const f4 gin = *(const f4*)(gi + b768 + 512 + c);
        const f4 ghr = *(const f4*)(gh + b768 + c);
        const f4 ghz = *(const f4*)(gh + b768 + 256 + c);
        const f4 ghn = *(const f4*)(gh + b768 + 512 + c);
        const f4 xv  = *(const f4*)(x + (size_t)row * DD + c);
        f4 hv;
        float s1 = 0.f, s2 = 0.f;
        #pragma unroll
        for (int u = 0; u < 4; ++u) {
            const float rr = 1.f / (1.f + expf(-(gir[u] + ghr[u])));
            const float zz = 1.f / (1.f + expf(-(giz[u] + ghz[u])));
            const float nn = tanhf(gin[u] + rr * ghn[u]);
            const float h = (1.f - zz) * nn + zz * xv[u];
            hv[u] = h;
            s1 += h;
            s2 += h * h;
        }
        #pragma unroll
        for (int off = 32; off; off >>= 1) {
            s1 += __shfl_xor(s1, off);
            s2 += __shfl_xor(s2, off);
        }
        const float mu  = s1 * (1.f / DD);
        const float var = s2 * (1.f / DD) - mu * mu;
        const float inv = rsqrtf(var + 1e-5f);
        const f4 gv = *(const f4*)(lng + c);
        const f4 bv = *(const f4*)(lnb + c);
        f4 res;
        #pragma unroll
        for (int u = 0; u < 4; ++u)
            res[u] = (hv[u] - mu) * inv * gv[u] + bv[u];
        *(f4*)(out + (size_t)row * DD + c) = res;
    }
}

extern "C" void kernel_launch(void* const* d_in, const int* in_sizes, int n_in,
                              void* d_out, int out_size, void* d_ws, size_t ws_size,
                              hipStream_t stream)
{
    const float* x    = (const float*)d_in[0];
    const float* adj0 = (const float*)d_in[1];
    const float* adj1 = (const float*)d_in[2];
    const float* w0   = (const float*)d_in[3];
    const float* w1   = (const float*)d_in[4];
    const float* Wm0  = (const float*)d_in[5];
    const float* bm0  = (const float*)d_in[6];
    const float* Wa0  = (const float*)d_in[7];
    const float* ba0  = (const float*)d_in[8];
    const float* Wm1  = (const float*)d_in[9];
    const float* bm1  = (const float*)d_in[10];
    const float* Wa1  = (const float*)d_in[11];
    const float* ba1  = (const float*)d_in[12];
    const float* wih  = (const float*)d_in[13];
    const float* whh  = (const float*)d_in[14];
    const float* bih  = (const float*)d_in[15];
    const float* bhh  = (const float*)d_in[16];
    const float* lng  = (const float*)d_in[17];
    const float* lnb  = (const float*)d_in[18];
    float* out = (float*)d_out;

    float* ws = (float*)d_ws;
    float* gh   = ws;            ws += (size_t)NN * 768;
    float* gi   = ws;            ws += (size_t)NN * 768;
    float* acur = ws;            ws += 2 * NN * HH;
    float* anb  = ws;            ws += 2 * NN * HH;
    int*   cnt  = (int*)ws;      ws += 2 * NN;
    int*   ej   = (int*)ws;      ws += 2 * NN * ECAP;
    ushort_t* wihb  = (ushort_t*)ws;  ws += (size_t)768 * 512 / 2;
    ushort_t* msgb  = (ushort_t*)ws;  ws += (size_t)NN * 512 / 2;
    ushort_t* mcatb = (ushort_t*)ws;  ws += (size_t)NN * 512 / 2;
    int* bar = (int*)ws;         ws += 16;

    hipMemsetAsync(bar, 0, 3 * sizeof(int), stream);
    mega_kernel<<<NBLK, 256, 0, stream>>>(
        x, adj0, adj1, w0, w1, Wm0, Wm1, whh, wih, Wa0, Wa1,
        bm0, bm1, bhh, ba0, ba1, bih, lng, lnb,
        cnt, ej, wihb, acur, anb, msgb, mcatb, gh, gi, out, bar);
}

// Round 3
// 216.012 us; speedup vs baseline: 2.7639x; 2.7639x over previous
//
#include <hip/hip_runtime.h>

#define NN 2048
#define DD 256
#define HH 4
#define ECAP 128

typedef unsigned short ushort_t;
typedef __attribute__((ext_vector_type(4))) unsigned short us4;
typedef __attribute__((ext_vector_type(8))) unsigned short us8;
typedef __attribute__((ext_vector_type(8))) short s8;
typedef __attribute__((ext_vector_type(4))) float f4;

__device__ __forceinline__ ushort_t f2b(float f) {   // fp32 -> bf16 bits, RNE
    unsigned int u = __float_as_uint(f);
    return (ushort_t)((u + 0x7fffu + ((u >> 16) & 1u)) >> 16);
}
__device__ __forceinline__ float b2f(ushort_t b) {
    return __uint_as_float(((unsigned int)b) << 16);
}
__device__ __forceinline__ void gl_lds16(const void* g, void* l) {
    __builtin_amdgcn_global_load_lds(
        (const __attribute__((address_space(1))) void*)g,
        (__attribute__((address_space(3))) void*)l, 16, 0, 0);
}

// ---------------------------------------------------------------------------
// bf16 gemm core, double-buffered gl_lds staging, XOR-swizzled [64][64] x2.
// ---------------------------------------------------------------------------
__device__ __forceinline__ void gemm_core_db(
    const ushort_t* __restrict__ A, int lda, const ushort_t* __restrict__ B, int ldb,
    int r0, int c0, int K, ushort_t (*as)[64], ushort_t (*bs)[64], f4 acc[2][2])
{
    const int t = threadIdx.x;
    const int wave = t >> 6, lane = t & 63;
    const int wm = (wave & 1) * 32, wn = (wave >> 1) * 32;
    const int fm = lane & 15, fq = lane >> 4;

    const int m0q0 = wave * 16 + (lane >> 3);
    const int m0q1 = m0q0 + 8;
    const int cs0 = ((lane & 7) ^ (m0q0 & 7)) * 8;
    const int cs1 = ((lane & 7) ^ (m0q1 & 7)) * 8;
    const ushort_t* ga0 = A + (size_t)(r0 + m0q0) * lda + cs0;
    const ushort_t* ga1 = A + (size_t)(r0 + m0q1) * lda + cs1;
    const ushort_t* gb0 = B + (size_t)(c0 + m0q0) * ldb + cs0;
    const ushort_t* gb1 = B + (size_t)(c0 + m0q1) * ldb + cs1;
    const int ra0 = wm + fm, ra1 = wm + 16 + fm;
    const int rb0 = wn + fm, rb1 = wn + 16 + fm;

    gl_lds16(ga0, &as[wave * 16][0]);
    gl_lds16(ga1, &as[wave * 16 + 8][0]);
    gl_lds16(gb0, &bs[wave * 16][0]);
    gl_lds16(gb1, &bs[wave * 16 + 8][0]);
    __syncthreads();

    int buf = 0;
    for (int k0 = 0; k0 < K; k0 += 64) {
        const int nb = buf ^ 64;
        if (k0 + 64 < K) {
            gl_lds16(ga0 + k0 + 64, &as[nb + wave * 16][0]);
            gl_lds16(ga1 + k0 + 64, &as[nb + wave * 16 + 8][0]);
            gl_lds16(gb0 + k0 + 64, &bs[nb + wave * 16][0]);
            gl_lds16(gb1 + k0 + 64, &bs[nb + wave * 16 + 8][0]);
        }
        #pragma unroll
        for (int kk = 0; kk < 2; ++kk) {
            const int cc = kk * 4 + fq;
            const s8 a0 = *(const s8*)&as[buf + ra0][(cc ^ (ra0 & 7)) * 8];
            const s8 a1 = *(const s8*)&as[buf + ra1][(cc ^ (ra1 & 7)) * 8];
            const s8 b0 = *(const s8*)&bs[buf + rb0][(cc ^ (rb0 & 7)) * 8];
            const s8 b1 = *(const s8*)&bs[buf + rb1][(cc ^ (rb1 & 7)) * 8];
            acc[0][0] = __builtin_amdgcn_mfma_f32_16x16x32_bf16(a0, b0, acc[0][0], 0, 0, 0);
            acc[0][1] = __builtin_amdgcn_mfma_f32_16x16x32_bf16(a0, b1, acc[0][1], 0, 0, 0);
            acc[1][0] = __builtin_amdgcn_mfma_f32_16x16x32_bf16(a1, b0, acc[1][0], 0, 0, 0);
            acc[1][1] = __builtin_amdgcn_mfma_f32_16x16x32_bf16(a1, b1, acc[1][1], 0, 0, 0);
        }
        __syncthreads();
        buf = nb;
    }
}

__device__ __forceinline__ us8 cvt8(float4 a, float4 b) {
    us8 o;
    o[0] = f2b(a.x); o[1] = f2b(a.y); o[2] = f2b(a.z); o[3] = f2b(a.w);
    o[4] = f2b(b.x); o[5] = f2b(b.y); o[6] = f2b(b.z); o[7] = f2b(b.w);
    return o;
}

// fp32-input gemm core, reg-prefetch (issue-early/write-late), same numerics.
__device__ __forceinline__ void gemm_core_f32(
    const float* __restrict__ A, int lda, const float* __restrict__ B, int ldb,
    int r0, int c0, int K, ushort_t (*as)[64], ushort_t (*bs)[64], f4 acc[2][2])
{
    const int t = threadIdx.x;
    const int wave = t >> 6, lane = t & 63;
    const int wm = (wave & 1) * 32, wn = (wave >> 1) * 32;
    const int fm = lane & 15, fq = lane >> 4;

    const int m1 = wave * 16 + (lane >> 3);
    const int m2 = m1 + 8;
    const int g1 = ((lane & 7) ^ (m1 & 7)) * 8;
    const int g2 = ((lane & 7) ^ (m2 & 7)) * 8;
    const int cl = (lane & 7) * 8;
    const int ra0 = wm + fm, ra1 = wm + 16 + fm;
    const int rb0 = wn + fm, rb1 = wn + 16 + fm;

    const float* pa1 = A + (size_t)(r0 + m1) * lda + g1;
    const float* pa2 = A + (size_t)(r0 + m2) * lda + g2;
    const float* pb1 = B + (size_t)(c0 + m1) * ldb + g1;
    const float* pb2 = B + (size_t)(c0 + m2) * ldb + g2;

    float4 aa0 = *(const float4*)(pa1);
    float4 aa1 = *(const float4*)(pa1 + 4);
    float4 ab0 = *(const float4*)(pa2);
    float4 ab1 = *(const float4*)(pa2 + 4);
    float4 ba0 = *(const float4*)(pb1);
    float4 ba1 = *(const float4*)(pb1 + 4);
    float4 bb0 = *(const float4*)(pb2);
    float4 bb1 = *(const float4*)(pb2 + 4);

    for (int k0 = 0; k0 < K; k0 += 64) {
        __syncthreads();
        *(us8*)&as[m1][cl] = cvt8(aa0, aa1);
        *(us8*)&as[m2][cl] = cvt8(ab0, ab1);
        *(us8*)&bs[m1][cl] = cvt8(ba0, ba1);
        *(us8*)&bs[m2][cl] = cvt8(bb0, bb1);
        __syncthreads();
        if (k0 + 64 < K) {
            aa0 = *(const float4*)(pa1 + k0 + 64);
            aa1 = *(const float4*)(pa1 + k0 + 68);
            ab0 = *(const float4*)(pa2 + k0 + 64);
            ab1 = *(const float4*)(pa2 + k0 + 68);
            ba0 = *(const float4*)(pb1 + k0 + 64);
            ba1 = *(const float4*)(pb1 + k0 + 68);
            bb0 = *(const float4*)(pb2 + k0 + 64);
            bb1 = *(const float4*)(pb2 + k0 + 68);
        }
        #pragma unroll
        for (int kk = 0; kk < 2; ++kk) {
            const int cc = kk * 4 + fq;
            const s8 a0 = *(const s8*)&as[ra0][(cc ^ (ra0 & 7)) * 8];
            const s8 a1 = *(const s8*)&as[ra1][(cc ^ (ra1 & 7)) * 8];
            const s8 b0 = *(const s8*)&bs[rb0][(cc ^ (rb0 & 7)) * 8];
            const s8 b1 = *(const s8*)&bs[rb1][(cc ^ (rb1 & 7)) * 8];
            acc[0][0] = __builtin_amdgcn_mfma_f32_16x16x32_bf16(a0, b0, acc[0][0], 0, 0, 0);
            acc[0][1] = __builtin_amdgcn_mfma_f32_16x16x32_bf16(a0, b1, acc[0][1], 0, 0, 0);
            acc[1][0] = __builtin_amdgcn_mfma_f32_16x16x32_bf16(a1, b0, acc[1][0], 0, 0, 0);
            acc[1][1] = __builtin_amdgcn_mfma_f32_16x16x32_bf16(a1, b1, acc[1][1], 0, 0, 0);
        }
    }
}

// ---------------------------------------------------------------------------
// K1 union (everything that reads only inputs):
//  [0,256)      edge scan   [256,384) attn_proj   [384,768) wih->bf16
//  [768,1408)   gemm1 tiles: [msg0|msg1|gh] = x @ [Wm0;Wm1;whh]^T + bias
// ---------------------------------------------------------------------------
#define E_SC  256
#define E_AP  384
#define E_WI  768
#define E_NB  1408

__global__ __launch_bounds__(256) void fused1_kernel(
    const float* __restrict__ x,
    const float* __restrict__ adj0, const float* __restrict__ adj1,
    const float* __restrict__ Wm0, const float* __restrict__ Wm1,
    const float* __restrict__ whh, const float* __restrict__ wih,
    const float* __restrict__ Wa0, const float* __restrict__ Wa1,
    const float* __restrict__ bm0, const float* __restrict__ bm1,
    const float* __restrict__ bhh,
    int* __restrict__ cnt, int* __restrict__ ej,
    ushort_t* __restrict__ wihb,
    float* __restrict__ acur, float* __restrict__ anb,
    ushort_t* __restrict__ msgb, float* __restrict__ gh)
{
    __shared__ char smem[16448];               // max(gemm 16384, attn_proj 16448)
    const int b = blockIdx.x, t = threadIdx.x;

    if (b < E_SC) {                            // ---- adj-only edge scan ----
        const int l = b & 1, chunk = b >> 1;
        const int i0 = chunk * 16;
        const float* adj = l ? adj1 : adj0;
        int* lcnt = (int*)smem;
        if (t < 16) lcnt[t] = 0;
        __syncthreads();
        const int rowLane = t >> 2, q = t & 3;
        for (int r0r = 0; r0r < NN; r0r += 512) {
            float4 a[8];
            #pragma unroll
            for (int it = 0; it < 8; ++it) {
                const int j = r0r + it * 64 + rowLane;
                a[it] = *(const float4*)(adj + (size_t)j * NN + i0 + q * 4);
            }
            #pragma unroll
            for (int it = 0; it < 8; ++it) {
                const int j = r0r + it * 64 + rowLane;
                const float av[4] = {a[it].x, a[it].y, a[it].z, a[it].w};
                #pragma unroll
                for (int u = 0; u < 4; ++u) {
                    if (av[u] != 0.f) {
                        const int li = q * 4 + u;
                        const int slot = atomicAdd(&lcnt[li], 1);
                        if (slot < ECAP)
                            ej[((size_t)l * NN + i0 + li) * ECAP + slot] = j;
                    }
                }
            }
        }
        __syncthreads();
        if (t < 16) cnt[l * NN + i0 + t] = min(lcnt[t], ECAP);
        return;
    }
    if (b < E_AP) {                            // ---- attn_proj ----
        float* sh = (float*)smem;              // [16][257]
        const int i0 = (b - E_SC) * 16;
        for (int rr = 0; rr < 16; ++rr)
            sh[rr * 257 + t] = x[(size_t)(i0 + rr) * DD + t];
        __syncthreads();
        const int r = t >> 4, idx = t & 15;
        const int l = idx >> 3, isnb = (idx >> 2) & 1, h = idx & 3;
        const float* wrow = (l ? Wa1 : Wa0) + h * (2 * DD) + isnb * DD;
        float acc = 0.f;
        for (int k = 0; k < DD; ++k) acc = fmaf(sh[r * 257 + k], wrow[k], acc);
        float* dst = isnb ? anb : acur;
        dst[((size_t)l * NN + i0 + r) * HH + h] = acc;
        return;
    }
    if (b < E_WI) {                            // ---- wih -> bf16 ----
        const int id = (b - E_AP) * 1024 + t * 4;
        const float4 v = *(const float4*)(wih + id);
        us4 o; o.x = f2b(v.x); o.y = f2b(v.y); o.z = f2b(v.z); o.w = f2b(v.w);
        *(us4*)(wihb + id) = o;
        return;
    }
    {                                          // ---- gemm1 tile (fp32 in) ----
        ushort_t (*as)[64] = (ushort_t(*)[64])smem;
        ushort_t (*bs)[64] = (ushort_t(*)[64])(smem + 8192);
        const int wave = t >> 6, lane = t & 63;
        const int wm = (wave & 1) * 32, wn = (wave >> 1) * 32;
        const int fm = lane & 15, fq = lane >> 4;
        const int idx = b - E_WI;
        const int c0 = (idx % 20) * 64, r0 = (idx / 20) * 64;
        const float* Bsrc = (c0 < 256) ? Wm0 + (size_t)c0 * DD
                          : (c0 < 512) ? Wm1 + (size_t)(c0 - 256) * DD
                                       : whh + (size_t)(c0 - 512) * DD;
        f4 acc[2][2] = {};
        gemm_core_f32(x, DD, Bsrc, DD, r0, 0, DD, as, bs, acc);
        // C/D layout (m89-verified): col = lane&15, row = (lane>>4)*4 + reg
        #pragma unroll
        for (int ni = 0; ni < 2; ++ni) {
            const int col = c0 + wn + ni * 16 + fm;
            const float bv = (col < 256) ? bm0[col]
                           : (col < 512) ? bm1[col - 256]
                                         : bhh[col - 512];
            #pragma unroll
            for (int mi = 0; mi < 2; ++mi) {
                #pragma unroll
                for (int r = 0; r < 4; ++r) {
                    const int row = r0 + wm + mi * 16 + fq * 4 + r;
                    const float v = acc[mi][ni][r] + bv;
                    if (col < 512) msgb[(size_t)row * 512 + col] = f2b(v);
                    else           gh[(size_t)row * 768 + col - 512] = v;
                }
            }
        }
    }
}

// ---------------------------------------------------------------------------
// K2 attn: gather w per edge, edge-only softmax, aggregate bf16 msg.
// ---------------------------------------------------------------------------
__global__ __launch_bounds__(256) void attn_kernel(
    const int* __restrict__ cnt, const int* __restrict__ ej,
    const float* __restrict__ w0, const float* __restrict__ w1,
    const float* __restrict__ acur, const float* __restrict__ anb,
    const float* __restrict__ ba0, const float* __restrict__ ba1,
    const ushort_t* __restrict__ msgb, ushort_t* __restrict__ mcatb)
{
    const int i = blockIdx.x, l = blockIdx.y, t = threadIdx.x;
    __shared__ float es[HH][ECAP];
    __shared__ int ejs[ECAP];
    const int ne = min(max(cnt[l * NN + i], 0), ECAP);
    const float* ba = l ? ba1 : ba0;
    const float* w  = l ? w1 : w0;
    const size_t ebase = ((size_t)l * NN + i) * ECAP;

    if (t < ne) {
        const int j = ej[ebase + t];
        const float wv = w[(size_t)j * NN + i];   // latency-parallel gather
        ejs[t] = j;
        const float4 av = *(const float4*)(anb + ((size_t)l * NN + j) * HH);
        const float sv[4] = {av.x, av.y, av.z, av.w};
        #pragma unroll
        for (int h = 0; h < HH; ++h) {
            float s = sv[h] + acur[((size_t)l * NN + i) * HH + h] + ba[h];
            s = (s > 0.f) ? s : 0.2f * s;           // leaky_relu(0.2)
            es[h][t] = s * wv;
        }
    }
    __syncthreads();
    {
        const int h = t >> 6, lane = t & 63;
        float s0 = (lane < ne) ? es[h][lane] : -1e30f;
        float s1 = (lane + 64 < ne) ? es[h][lane + 64] : -1e30f;
        float m = fmaxf(s0, s1);
        #pragma unroll
        for (int off = 32; off; off >>= 1) m = fmaxf(m, __shfl_xor(m, off));
        const float p0 = expf(s0 - m), p1 = expf(s1 - m);
        float sum = p0 + p1;
        #pragma unroll
        for (int off = 32; off; off >>= 1) sum += __shfl_xor(sum, off);
        const float inv = (ne > 0) ? 1.f / sum : 0.f;
        es[h][lane] = p0 * inv;
        if (lane + 64 < ECAP) es[h][lane + 64] = p1 * inv;
    }
    __syncthreads();
    const int h = t >> 6;
    const int off = l * DD + t;
    float acc = 0.f;
    int e = 0;
    for (; e + 8 <= ne; e += 8) {
        float v[8];
        #pragma unroll
        for (int u = 0; u < 8; ++u)
            v[u] = b2f(msgb[(size_t)ejs[e + u] * 512 + off]);
        #pragma unroll
        for (int u = 0; u < 8; ++u)
            acc = fmaf(es[h][e + u], v[u], acc);
    }
    for (; e < ne; ++e)
        acc = fmaf(es[h][e], b2f(msgb[(size_t)ejs[e] * 512 + off]), acc);
    mcatb[(size_t)i * (2 * DD) + off] = f2b(acc);
}

// ---------------------------------------------------------------------------
// K3: gemm2 + fused gates/LN epilogue via per-row-panel tile counter.
// grid = (12 col-tiles, 32 row-panels). Each block computes its 64x64 gi
// tile; the 12th arriver per row-panel (device-scope atomic) runs gates+LN
// for the panel's 64 rows. No spinning; 384 release-fences + 32 acquires.
// ---------------------------------------------------------------------------
__global__ __launch_bounds__(256) void gemm2_gates(
    const ushort_t* __restrict__ mcatb, const ushort_t* __restrict__ wihb,
    const float* __restrict__ bih, float* __restrict__ gi,
    const float* __restrict__ gh, const float* __restrict__ x,
    const float* __restrict__ lng, const float* __restrict__ lnb,
    float* __restrict__ out, int* __restrict__ tilecnt)
{
    __shared__ ushort_t as[128][64];           // 2 buffers of 64 rows
    __shared__ ushort_t bs[128][64];
    __shared__ int last_flag;
    const int t = threadIdx.x;
    const int wave = t >> 6, lane = t & 63;
    const int wm = (wave & 1) * 32, wn = (wave >> 1) * 32;
    const int fm = lane & 15, fq = lane >> 4;
    const int c0 = blockIdx.x * 64, r0 = blockIdx.y * 64;
    f4 acc[2][2] = {};
    gemm_core_db(mcatb, 512, wihb, 512, r0, c0, 512, as, bs, acc);
    #pragma unroll
    for (int ni = 0; ni < 2; ++ni) {
        const int col = c0 + wn + ni * 16 + fm;
        const float bv = bih[col];
        #pragma unroll
        for (int mi = 0; mi < 2; ++mi)
            #pragma unroll
            for (int r = 0; r < 4; ++r)
                gi[(size_t)(r0 + wm + mi * 16 + fq * 4 + r) * 768 + col] =
                    acc[mi][ni][r] + bv;
    }
    // ---- tile-counter handoff ----
    __syncthreads();                           // all 256 threads' gi stores drained (vmcnt0)
    if (t == 0) {
        __threadfence();                       // publish this block's gi tile (release)
        const int old = __hip_atomic_fetch_add(&tilecnt[blockIdx.y], 1,
                           __ATOMIC_ACQ_REL, __HIP_MEMORY_SCOPE_AGENT);
        if (old == 11) __threadfence();        // acquire: invalidate stale gi lines
        last_flag = (old == 11);
    }
    __syncthreads();
    if (!last_flag) return;

    // ---- gates + LN for rows [r0, r0+64): wave wv does 16 consecutive rows.
    const int c = lane * 4;
    const f4 gv = *(const f4*)(lng + c);
    const f4 bvv = *(const f4*)(lnb + c);
    for (int it = 0; it < 16; ++it) {
        const int row = r0 + wave * 16 + it;
        const size_t b768 = (size_t)row * 768;
        const f4 gir = *(const f4*)(gi + b768 + c);
        const f4 giz = *(const f4*)(gi + b768 + 256 + c);
        const f4 gin = *(const f4*)(gi + b768 + 512 + c);
        const f4 ghr = *(const f4*)(gh + b768 + c);
        const f4 ghz = *(const f4*)(gh + b768 + 256 + c);
        const f4 ghn = *(const f4*)(gh + b768 + 512 + c);
        const f4 xv  = *(const f4*)(x + (size_t)row * DD + c);
        f4 hv;
        float s1 = 0.f, s2 = 0.f;
        #pragma unroll
        for (int u = 0; u < 4; ++u) {
            const float rr = 1.f / (1.f + expf(-(gir[u] + ghr[u])));
            const float zz = 1.f / (1.f + expf(-(giz[u] + ghz[u])));
            const float nn = tanhf(gin[u] + rr * ghn[u]);
            const float h = (1.f - zz) * nn + zz * xv[u];
            hv[u] = h;
            s1 += h;
            s2 += h * h;
        }
        #pragma unroll
        for (int off = 32; off; off >>= 1) {
            s1 += __shfl_xor(s1, off);
            s2 += __shfl_xor(s2, off);
        }
        const float mu  = s1 * (1.f / DD);
        const float var = s2 * (1.f / DD) - mu * mu;
        const float inv = rsqrtf(var + 1e-5f);
        f4 res;
        #pragma unroll
        for (int u = 0; u < 4; ++u)
            res[u] = (hv[u] - mu) * inv * gv[u] + bvv[u];
        *(f4*)(out + (size_t)row * DD + c) = res;
    }
}

extern "C" void kernel_launch(void* const* d_in, const int* in_sizes, int n_in,
                              void* d_out, int out_size, void* d_ws, size_t ws_size,
                              hipStream_t stream)
{
    const float* x    = (const float*)d_in[0];
    const float* adj0 = (const float*)d_in[1];
    const float* adj1 = (const float*)d_in[2];
    const float* w0   = (const float*)d_in[3];
    const float* w1   = (const float*)d_in[4];
    const float* Wm0  = (const float*)d_in[5];
    const float* bm0  = (const float*)d_in[6];
    const float* Wa0  = (const float*)d_in[7];
    const float* ba0  = (const float*)d_in[8];
    const float* Wm1  = (const float*)d_in[9];
    const float* bm1  = (const float*)d_in[10];
    const float* Wa1  = (const float*)d_in[11];
    const float* ba1  = (const float*)d_in[12];
    const float* wih  = (const float*)d_in[13];
    const float* whh  = (const float*)d_in[14];
    const float* bih  = (const float*)d_in[15];
    const float* bhh  = (const float*)d_in[16];
    const float* lng  = (const float*)d_in[17];
    const float* lnb  = (const float*)d_in[18];
    float* out = (float*)d_out;

    float* ws = (float*)d_ws;
    float* gh   = ws;            ws += (size_t)NN * 768;
    float* gi   = ws;            ws += (size_t)NN * 768;
    float* acur = ws;            ws += 2 * NN * HH;
    float* anb  = ws;            ws += 2 * NN * HH;
    int*   cnt  = (int*)ws;      ws += 2 * NN;
    int*   ej   = (int*)ws;      ws += 2 * NN * ECAP;
    ushort_t* wihb  = (ushort_t*)ws;  ws += (size_t)768 * 512 / 2;
    ushort_t* msgb  = (ushort_t*)ws;  ws += (size_t)NN * 512 / 2;
    ushort_t* mcatb = (ushort_t*)ws;  ws += (size_t)NN * 512 / 2;
    int* tilecnt = (int*)ws;     ws += 32;

    hipMemsetAsync(tilecnt, 0, 32 * sizeof(int), stream);
    fused1_kernel<<<E_NB, 256, 0, stream>>>(
        x, adj0, adj1, Wm0, Wm1, whh, wih, Wa0, Wa1, bm0, bm1, bhh,
        cnt, ej, wihb, acur, anb, msgb, gh);
    attn_kernel<<<dim3(NN, 2), 256, 0, stream>>>(
        cnt, ej, w0, w1, acur, anb, ba0, ba1, msgb, mcatb);
    gemm2_gates<<<dim3(12, 32), 256, 0, stream>>>(
        mcatb, wihb, bih, gi, gh, x, lng, lnb, out, tilecnt);
}

// Round 4
// 175.416 us; speedup vs baseline: 3.4035x; 1.2314x over previous
//
#include <hip/hip_runtime.h>

#define NN 2048
#define DD 256
#define HH 4
#define ECAP 128

typedef unsigned short ushort_t;
typedef __attribute__((ext_vector_type(4))) unsigned short us4;
typedef __attribute__((ext_vector_type(8))) unsigned short us8;
typedef __attribute__((ext_vector_type(8))) short s8;
typedef __attribute__((ext_vector_type(4))) float f4;

__device__ __forceinline__ ushort_t f2b(float f) {   // fp32 -> bf16 bits, RNE
    unsigned int u = __float_as_uint(f);
    return (ushort_t)((u + 0x7fffu + ((u >> 16) & 1u)) >> 16);
}
__device__ __forceinline__ float b2f(ushort_t b) {
    return __uint_as_float(((unsigned int)b) << 16);
}
__device__ __forceinline__ void gl_lds16(const void* g, void* l) {
    __builtin_amdgcn_global_load_lds(
        (const __attribute__((address_space(1))) void*)g,
        (__attribute__((address_space(3))) void*)l, 16, 0, 0);
}

// ---------------------------------------------------------------------------
// bf16 gemm core, double-buffered gl_lds staging, XOR-swizzled [64][64] x2.
// ---------------------------------------------------------------------------
__device__ __forceinline__ void gemm_core_db(
    const ushort_t* __restrict__ A, int lda, const ushort_t* __restrict__ B, int ldb,
    int r0, int c0, int K, ushort_t (*as)[64], ushort_t (*bs)[64], f4 acc[2][2])
{
    const int t = threadIdx.x;
    const int wave = t >> 6, lane = t & 63;
    const int wm = (wave & 1) * 32, wn = (wave >> 1) * 32;
    const int fm = lane & 15, fq = lane >> 4;

    const int m0q0 = wave * 16 + (lane >> 3);
    const int m0q1 = m0q0 + 8;
    const int cs0 = ((lane & 7) ^ (m0q0 & 7)) * 8;
    const int cs1 = ((lane & 7) ^ (m0q1 & 7)) * 8;
    const ushort_t* ga0 = A + (size_t)(r0 + m0q0) * lda + cs0;
    const ushort_t* ga1 = A + (size_t)(r0 + m0q1) * lda + cs1;
    const ushort_t* gb0 = B + (size_t)(c0 + m0q0) * ldb + cs0;
    const ushort_t* gb1 = B + (size_t)(c0 + m0q1) * ldb + cs1;
    const int ra0 = wm + fm, ra1 = wm + 16 + fm;
    const int rb0 = wn + fm, rb1 = wn + 16 + fm;

    gl_lds16(ga0, &as[wave * 16][0]);
    gl_lds16(ga1, &as[wave * 16 + 8][0]);
    gl_lds16(gb0, &bs[wave * 16][0]);
    gl_lds16(gb1, &bs[wave * 16 + 8][0]);
    __syncthreads();

    int buf = 0;
    for (int k0 = 0; k0 < K; k0 += 64) {
        const int nb = buf ^ 64;
        if (k0 + 64 < K) {
            gl_lds16(ga0 + k0 + 64, &as[nb + wave * 16][0]);
            gl_lds16(ga1 + k0 + 64, &as[nb + wave * 16 + 8][0]);
            gl_lds16(gb0 + k0 + 64, &bs[nb + wave * 16][0]);
            gl_lds16(gb1 + k0 + 64, &bs[nb + wave * 16 + 8][0]);
        }
        #pragma unroll
        for (int kk = 0; kk < 2; ++kk) {
            const int cc = kk * 4 + fq;
            const s8 a0 = *(const s8*)&as[buf + ra0][(cc ^ (ra0 & 7)) * 8];
            const s8 a1 = *(const s8*)&as[buf + ra1][(cc ^ (ra1 & 7)) * 8];
            const s8 b0 = *(const s8*)&bs[buf + rb0][(cc ^ (rb0 & 7)) * 8];
            const s8 b1 = *(const s8*)&bs[buf + rb1][(cc ^ (rb1 & 7)) * 8];
            acc[0][0] = __builtin_amdgcn_mfma_f32_16x16x32_bf16(a0, b0, acc[0][0], 0, 0, 0);
            acc[0][1] = __builtin_amdgcn_mfma_f32_16x16x32_bf16(a0, b1, acc[0][1], 0, 0, 0);
            acc[1][0] = __builtin_amdgcn_mfma_f32_16x16x32_bf16(a1, b0, acc[1][0], 0, 0, 0);
            acc[1][1] = __builtin_amdgcn_mfma_f32_16x16x32_bf16(a1, b1, acc[1][1], 0, 0, 0);
        }
        __syncthreads();
        buf = nb;
    }
}

__device__ __forceinline__ us8 cvt8(float4 a, float4 b) {
    us8 o;
    o[0] = f2b(a.x); o[1] = f2b(a.y); o[2] = f2b(a.z); o[3] = f2b(a.w);
    o[4] = f2b(b.x); o[5] = f2b(b.y); o[6] = f2b(b.z); o[7] = f2b(b.w);
    return o;
}

// fp32-input gemm core, reg-prefetch (issue-early/write-late), same numerics.
__device__ __forceinline__ void gemm_core_f32(
    const float* __restrict__ A, int lda, const float* __restrict__ B, int ldb,
    int r0, int c0, int K, ushort_t (*as)[64], ushort_t (*bs)[64], f4 acc[2][2])
{
    const int t = threadIdx.x;
    const int wave = t >> 6, lane = t & 63;
    const int wm = (wave & 1) * 32, wn = (wave >> 1) * 32;
    const int fm = lane & 15, fq = lane >> 4;

    const int m1 = wave * 16 + (lane >> 3);
    const int m2 = m1 + 8;
    const int g1 = ((lane & 7) ^ (m1 & 7)) * 8;
    const int g2 = ((lane & 7) ^ (m2 & 7)) * 8;
    const int cl = (lane & 7) * 8;
    const int ra0 = wm + fm, ra1 = wm + 16 + fm;
    const int rb0 = wn + fm, rb1 = wn + 16 + fm;

    const float* pa1 = A + (size_t)(r0 + m1) * lda + g1;
    const float* pa2 = A + (size_t)(r0 + m2) * lda + g2;
    const float* pb1 = B + (size_t)(c0 + m1) * ldb + g1;
    const float* pb2 = B + (size_t)(c0 + m2) * ldb + g2;

    float4 aa0 = *(const float4*)(pa1);
    float4 aa1 = *(const float4*)(pa1 + 4);
    float4 ab0 = *(const float4*)(pa2);
    float4 ab1 = *(const float4*)(pa2 + 4);
    float4 ba0 = *(const float4*)(pb1);
    float4 ba1 = *(const float4*)(pb1 + 4);
    float4 bb0 = *(const float4*)(pb2);
    float4 bb1 = *(const float4*)(pb2 + 4);

    for (int k0 = 0; k0 < K; k0 += 64) {
        __syncthreads();
        *(us8*)&as[m1][cl] = cvt8(aa0, aa1);
        *(us8*)&as[m2][cl] = cvt8(ab0, ab1);
        *(us8*)&bs[m1][cl] = cvt8(ba0, ba1);
        *(us8*)&bs[m2][cl] = cvt8(bb0, bb1);
        __syncthreads();
        if (k0 + 64 < K) {
            aa0 = *(const float4*)(pa1 + k0 + 64);
            aa1 = *(const float4*)(pa1 + k0 + 68);
            ab0 = *(const float4*)(pa2 + k0 + 64);
            ab1 = *(const float4*)(pa2 + k0 + 68);
            ba0 = *(const float4*)(pb1 + k0 + 64);
            ba1 = *(const float4*)(pb1 + k0 + 68);
            bb0 = *(const float4*)(pb2 + k0 + 64);
            bb1 = *(const float4*)(pb2 + k0 + 68);
        }
        #pragma unroll
        for (int kk = 0; kk < 2; ++kk) {
            const int cc = kk * 4 + fq;
            const s8 a0 = *(const s8*)&as[ra0][(cc ^ (ra0 & 7)) * 8];
            const s8 a1 = *(const s8*)&as[ra1][(cc ^ (ra1 & 7)) * 8];
            const s8 b0 = *(const s8*)&bs[rb0][(cc ^ (rb0 & 7)) * 8];
            const s8 b1 = *(const s8*)&bs[rb1][(cc ^ (rb1 & 7)) * 8];
            acc[0][0] = __builtin_amdgcn_mfma_f32_16x16x32_bf16(a0, b0, acc[0][0], 0, 0, 0);
            acc[0][1] = __builtin_amdgcn_mfma_f32_16x16x32_bf16(a0, b1, acc[0][1], 0, 0, 0);
            acc[1][0] = __builtin_amdgcn_mfma_f32_16x16x32_bf16(a1, b0, acc[1][0], 0, 0, 0);
            acc[1][1] = __builtin_amdgcn_mfma_f32_16x16x32_bf16(a1, b1, acc[1][1], 0, 0, 0);
        }
    }
}

// ---------------------------------------------------------------------------
// K1 union:
//  [0,256)      edge scan + TAIL w-GATHER: after listing edges, the block
//               batch-gathers w[j,i] for its ~500 edges with full 256-thread
//               parallelism into compact ewt[l][i][slot]. This hoists attn's
//               18MB random HBM gather into fused1 (overlaps gemm1 blocks).
//               ej slot order unchanged -> downstream folds bit-identical.
//  [256,384)    attn_proj   [384,768) wih->bf16
//  [768,1408)   gemm1 tiles: [msg0|msg1|gh] = x @ [Wm0;Wm1;whh]^T + bias
// ---------------------------------------------------------------------------
#define E_SC  256
#define E_AP  384
#define E_WI  768
#define E_NB  1408

__global__ __launch_bounds__(256) void fused1_kernel(
    const float* __restrict__ x,
    const float* __restrict__ adj0, const float* __restrict__ adj1,
    const float* __restrict__ w0, const float* __restrict__ w1,
    const float* __restrict__ Wm0, const float* __restrict__ Wm1,
    const float* __restrict__ whh, const float* __restrict__ wih,
    const float* __restrict__ Wa0, const float* __restrict__ Wa1,
    const float* __restrict__ bm0, const float* __restrict__ bm1,
    const float* __restrict__ bhh,
    int* __restrict__ cnt, int* __restrict__ ej, float* __restrict__ ewt,
    ushort_t* __restrict__ wihb,
    float* __restrict__ acur, float* __restrict__ anb,
    ushort_t* __restrict__ msgb, float* __restrict__ gh)
{
    __shared__ char smem[16448];               // max(gemm 16384, attn_proj 16448)
    const int b = blockIdx.x, t = threadIdx.x;

    if (b < E_SC) {                            // ---- adj-only edge scan ----
        const int l = b & 1, chunk = b >> 1;
        const int i0 = chunk * 16;
        const float* adj = l ? adj1 : adj0;
        const float* w   = l ? w1 : w0;
        int* lcnt = (int*)smem;
        if (t < 16) lcnt[t] = 0;
        __syncthreads();
        const int rowLane = t >> 2, q = t & 3;
        for (int r0r = 0; r0r < NN; r0r += 512) {
            float4 a[8];
            #pragma unroll
            for (int it = 0; it < 8; ++it) {
                const int j = r0r + it * 64 + rowLane;
                a[it] = *(const float4*)(adj + (size_t)j * NN + i0 + q * 4);
            }
            #pragma unroll
            for (int it = 0; it < 8; ++it) {
                const int j = r0r + it * 64 + rowLane;
                const float av[4] = {a[it].x, a[it].y, a[it].z, a[it].w};
                #pragma unroll
                for (int u = 0; u < 4; ++u) {
                    if (av[u] != 0.f) {
                        const int li = q * 4 + u;
                        const int slot = atomicAdd(&lcnt[li], 1);
                        if (slot < ECAP)
                            ej[((size_t)l * NN + i0 + li) * ECAP + slot] = j;
                    }
                }
            }
        }
        __syncthreads();
        if (t < 16) cnt[l * NN + i0 + t] = min(lcnt[t], ECAP);
        // ---- tail w-gather: flat loop over 16 lists x ECAP slots ----
        for (int s = t; s < 16 * ECAP; s += 256) {
            const int li = s >> 7, sl = s & (ECAP - 1);
            if (sl < min(lcnt[li], ECAP)) {
                const size_t base = ((size_t)l * NN + i0 + li) * ECAP + sl;
                const int j = ej[base];
                ewt[base] = w[(size_t)j * NN + i0 + li];
            }
        }
        return;
    }
    if (b < E_AP) {                            // ---- attn_proj ----
        float* sh = (float*)smem;              // [16][257]
        const int i0 = (b - E_SC) * 16;
        for (int rr = 0; rr < 16; ++rr)
            sh[rr * 257 + t] = x[(size_t)(i0 + rr) * DD + t];
        __syncthreads();
        const int r = t >> 4, idx = t & 15;
        const int l = idx >> 3, isnb = (idx >> 2) & 1, h = idx & 3;
        const float* wrow = (l ? Wa1 : Wa0) + h * (2 * DD) + isnb * DD;
        float acc = 0.f;
        for (int k = 0; k < DD; ++k) acc = fmaf(sh[r * 257 + k], wrow[k], acc);
        float* dst = isnb ? anb : acur;
        dst[((size_t)l * NN + i0 + r) * HH + h] = acc;
        return;
    }
    if (b < E_WI) {                            // ---- wih -> bf16 ----
        const int id = (b - E_AP) * 1024 + t * 4;
        const float4 v = *(const float4*)(wih + id);
        us4 o; o.x = f2b(v.x); o.y = f2b(v.y); o.z = f2b(v.z); o.w = f2b(v.w);
        *(us4*)(wihb + id) = o;
        return;
    }
    {                                          // ---- gemm1 tile (fp32 in) ----
        ushort_t (*as)[64] = (ushort_t(*)[64])smem;
        ushort_t (*bs)[64] = (ushort_t(*)[64])(smem + 8192);
        const int wave = t >> 6, lane = t & 63;
        const int wm = (wave & 1) * 32, wn = (wave >> 1) * 32;
        const int fm = lane & 15, fq = lane >> 4;
        const int idx = b - E_WI;
        const int c0 = (idx % 20) * 64, r0 = (idx / 20) * 64;
        const float* Bsrc = (c0 < 256) ? Wm0 + (size_t)c0 * DD
                          : (c0 < 512) ? Wm1 + (size_t)(c0 - 256) * DD
                                       : whh + (size_t)(c0 - 512) * DD;
        f4 acc[2][2] = {};
        gemm_core_f32(x, DD, Bsrc, DD, r0, 0, DD, as, bs, acc);
        // C/D layout (m89-verified): col = lane&15, row = (lane>>4)*4 + reg
        #pragma unroll
        for (int ni = 0; ni < 2; ++ni) {
            const int col = c0 + wn + ni * 16 + fm;
            const float bv = (col < 256) ? bm0[col]
                           : (col < 512) ? bm1[col - 256]
                                         : bhh[col - 512];
            #pragma unroll
            for (int mi = 0; mi < 2; ++mi) {
                #pragma unroll
                for (int r = 0; r < 4; ++r) {
                    const int row = r0 + wm + mi * 16 + fq * 4 + r;
                    const float v = acc[mi][ni][r] + bv;
                    if (col < 512) msgb[(size_t)row * 512 + col] = f2b(v);
                    else           gh[(size_t)row * 768 + col - 512] = v;
                }
            }
        }
    }
}

// ---------------------------------------------------------------------------
// K2 attn: w now read from compact ewt (sequential, L2-resident) instead of
// the 18MB random gather. Same arithmetic, same fold order.
// ---------------------------------------------------------------------------
__global__ __launch_bounds__(256) void attn_kernel(
    const int* __restrict__ cnt, const int* __restrict__ ej,
    const float* __restrict__ ewt,
    const float* __restrict__ acur, const float* __restrict__ anb,
    const float* __restrict__ ba0, const float* __restrict__ ba1,
    const ushort_t* __restrict__ msgb, ushort_t* __restrict__ mcatb)
{
    const int i = blockIdx.x, l = blockIdx.y, t = threadIdx.x;
    __shared__ float es[HH][ECAP];
    __shared__ int ejs[ECAP];
    const int ne = min(max(cnt[l * NN + i], 0), ECAP);
    const float* ba = l ? ba1 : ba0;
    const size_t ebase = ((size_t)l * NN + i) * ECAP;

    if (t < ne) {
        const int j = ej[ebase + t];
        const float wv = ewt[ebase + t];          // compact, L2-resident
        ejs[t] = j;
        const float4 av = *(const float4*)(anb + ((size_t)l * NN + j) * HH);
        const float sv[4] = {av.x, av.y, av.z, av.w};
        #pragma unroll
        for (int h = 0; h < HH; ++h) {
            float s = sv[h] + acur[((size_t)l * NN + i) * HH + h] + ba[h];
            s = (s > 0.f) ? s : 0.2f * s;           // leaky_relu(0.2)
            es[h][t] = s * wv;
        }
    }
    __syncthreads();
    {
        const int h = t >> 6, lane = t & 63;
        float s0 = (lane < ne) ? es[h][lane] : -1e30f;
        float s1 = (lane + 64 < ne) ? es[h][lane + 64] : -1e30f;
        float m = fmaxf(s0, s1);
        #pragma unroll
        for (int off = 32; off; off >>= 1) m = fmaxf(m, __shfl_xor(m, off));
        const float p0 = expf(s0 - m), p1 = expf(s1 - m);
        float sum = p0 + p1;
        #pragma unroll
        for (int off = 32; off; off >>= 1) sum += __shfl_xor(sum, off);
        const float inv = (ne > 0) ? 1.f / sum : 0.f;
        es[h][lane] = p0 * inv;
        if (lane + 64 < ECAP) es[h][lane + 64] = p1 * inv;
    }
    __syncthreads();
    const int h = t >> 6;
    const int off = l * DD + t;
    float acc = 0.f;
    int e = 0;
    for (; e + 8 <= ne; e += 8) {
        float v[8];
        #pragma unroll
        for (int u = 0; u < 8; ++u)
            v[u] = b2f(msgb[(size_t)ejs[e + u] * 512 + off]);
        #pragma unroll
        for (int u = 0; u < 8; ++u)
            acc = fmaf(es[h][e + u], v[u], acc);
    }
    for (; e < ne; ++e)
        acc = fmaf(es[h][e], b2f(msgb[(size_t)ejs[e] * 512 + off]), acc);
    mcatb[(size_t)i * (2 * DD) + off] = f2b(acc);
}

// ---------------------------------------------------------------------------
// K3: gemm2: gi[2048,768] = mcatb @ wihb^T + bih   (K=512, bf16 dbuf core)
// ---------------------------------------------------------------------------
__global__ __launch_bounds__(256) void gemm2_kernel(
    const ushort_t* __restrict__ mcatb, const ushort_t* __restrict__ wihb,
    const float* __restrict__ bih, float* __restrict__ gi)
{
    __shared__ ushort_t as[128][64];
    __shared__ ushort_t bs[128][64];
    const int t = threadIdx.x;
    const int wave = t >> 6, lane = t & 63;
    const int wm = (wave & 1) * 32, wn = (wave >> 1) * 32;
    const int fm = lane & 15, fq = lane >> 4;
    const int c0 = blockIdx.x * 64, r0 = blockIdx.y * 64;
    f4 acc[2][2] = {};
    gemm_core_db(mcatb, 512, wihb, 512, r0, c0, 512, as, bs, acc);
    #pragma unroll
    for (int ni = 0; ni < 2; ++ni) {
        const int col = c0 + wn + ni * 16 + fm;
        const float bv = bih[col];
        #pragma unroll
        for (int mi = 0; mi < 2; ++mi)
            #pragma unroll
            for (int r = 0; r < 4; ++r)
                gi[(size_t)(r0 + wm + mi * 16 + fq * 4 + r) * 768 + col] =
                    acc[mi][ni][r] + bv;
    }
}

// ---------------------------------------------------------------------------
// K4: GRU gates + LayerNorm. One row per wave, float4 I/O, shuffle-only
// reduction, zero barriers.
// ---------------------------------------------------------------------------
__global__ __launch_bounds__(256) void gates_ln(
    const float* __restrict__ gi, const float* __restrict__ gh, const float* __restrict__ x,
    const float* __restrict__ lng, const float* __restrict__ lnb, float* __restrict__ out)
{
    const int t = threadIdx.x;
    const int lane = t & 63, wv = t >> 6;
    const int row = blockIdx.x * 4 + wv;
    const size_t b768 = (size_t)row * 768;
    const int c = lane * 4;
    const f4 gir = *(const f4*)(gi + b768 + c);
    const f4 giz = *(const f4*)(gi + b768 + 256 + c);
    const f4 gin = *(const f4*)(gi + b768 + 512 + c);
    const f4 ghr = *(const f4*)(gh + b768 + c);
    const f4 ghz = *(const f4*)(gh + b768 + 256 + c);
    const f4 ghn = *(const f4*)(gh + b768 + 512 + c);
    const f4 xv  = *(const f4*)(x + (size_t)row * DD + c);
    f4 hv;
    float s1 = 0.f, s2 = 0.f;
    #pragma unroll
    for (int u = 0; u < 4; ++u) {
        const float rr = 1.f / (1.f + expf(-(gir[u] + ghr[u])));
        const float zz = 1.f / (1.f + expf(-(giz[u] + ghz[u])));
        const float nn = tanhf(gin[u] + rr * ghn[u]);
        const float h = (1.f - zz) * nn + zz * xv[u];
        hv[u] = h;
        s1 += h;
        s2 += h * h;
    }
    #pragma unroll
    for (int off = 32; off; off >>= 1) {
        s1 += __shfl_xor(s1, off);
        s2 += __shfl_xor(s2, off);
    }
    const float mu  = s1 * (1.f / DD);
    const float var = s2 * (1.f / DD) - mu * mu;
    const float inv = rsqrtf(var + 1e-5f);
    const f4 gv = *(const f4*)(lng + c);
    const f4 bv = *(const f4*)(lnb + c);
    f4 res;
    #pragma unroll
    for (int u = 0; u < 4; ++u)
        res[u] = (hv[u] - mu) * inv * gv[u] + bv[u];
    *(f4*)(out + (size_t)row * DD + c) = res;
}

extern "C" void kernel_launch(void* const* d_in, const int* in_sizes, int n_in,
                              void* d_out, int out_size, void* d_ws, size_t ws_size,
                              hipStream_t stream)
{
    const float* x    = (const float*)d_in[0];
    const float* adj0 = (const float*)d_in[1];
    const float* adj1 = (const float*)d_in[2];
    const float* w0   = (const float*)d_in[3];
    const float* w1   = (const float*)d_in[4];
    const float* Wm0  = (const float*)d_in[5];
    const float* bm0  = (const float*)d_in[6];
    const float* Wa0  = (const float*)d_in[7];
    const float* ba0  = (const float*)d_in[8];
    const float* Wm1  = (const float*)d_in[9];
    const float* bm1  = (const float*)d_in[10];
    const float* Wa1  = (const float*)d_in[11];
    const float* ba1  = (const float*)d_in[12];
    const float* wih  = (const float*)d_in[13];
    const float* whh  = (const float*)d_in[14];
    const float* bih  = (const float*)d_in[15];
    const float* bhh  = (const float*)d_in[16];
    const float* lng  = (const float*)d_in[17];
    const float* lnb  = (const float*)d_in[18];
    float* out = (float*)d_out;

    float* ws = (float*)d_ws;
    float* gh   = ws;            ws += (size_t)NN * 768;
    float* gi   = ws;            ws += (size_t)NN * 768;
    float* acur = ws;            ws += 2 * NN * HH;
    float* anb  = ws;            ws += 2 * NN * HH;
    int*   cnt  = (int*)ws;      ws += 2 * NN;
    int*   ej   = (int*)ws;      ws += 2 * NN * ECAP;
    float* ewt  = ws;            ws += 2 * NN * ECAP;
    ushort_t* wihb  = (ushort_t*)ws;  ws += (size_t)768 * 512 / 2;
    ushort_t* msgb  = (ushort_t*)ws;  ws += (size_t)NN * 512 / 2;
    ushort_t* mcatb = (ushort_t*)ws;  ws += (size_t)NN * 512 / 2;

    fused1_kernel<<<E_NB, 256, 0, stream>>>(
        x, adj0, adj1, w0, w1, Wm0, Wm1, whh, wih, Wa0, Wa1, bm0, bm1, bhh,
        cnt, ej, ewt, wihb, acur, anb, msgb, gh);
    attn_kernel<<<dim3(NN, 2), 256, 0, stream>>>(
        cnt, ej, ewt, acur, anb, ba0, ba1, msgb, mcatb);
    gemm2_kernel<<<dim3(12, 32), 256, 0, stream>>>(mcatb, wihb, bih, gi);
    gates_ln<<<NN / 4, 256, 0, stream>>>(gi, gh, x, lng, lnb, out);
}

// Round 5
// 167.558 us; speedup vs baseline: 3.5631x; 1.0469x over previous
//
#include <hip/hip_runtime.h>

#define NN 2048
#define DD 256
#define HH 4
#define ECAP 128

typedef unsigned short ushort_t;
typedef __attribute__((ext_vector_type(4))) unsigned short us4;
typedef __attribute__((ext_vector_type(8))) unsigned short us8;
typedef __attribute__((ext_vector_type(8))) short s8;
typedef __attribute__((ext_vector_type(4))) float f4;

__device__ __forceinline__ ushort_t f2b(float f) {   // fp32 -> bf16 bits, RNE
    unsigned int u = __float_as_uint(f);
    return (ushort_t)((u + 0x7fffu + ((u >> 16) & 1u)) >> 16);
}
__device__ __forceinline__ float b2f(ushort_t b) {
    return __uint_as_float(((unsigned int)b) << 16);
}
__device__ __forceinline__ void gl_lds16(const void* g, void* l) {
    __builtin_amdgcn_global_load_lds(
        (const __attribute__((address_space(1))) void*)g,
        (__attribute__((address_space(3))) void*)l, 16, 0, 0);
}

__device__ __forceinline__ us8 cvt8(float4 a, float4 b) {
    us8 o;
    o[0] = f2b(a.x); o[1] = f2b(a.y); o[2] = f2b(a.z); o[3] = f2b(a.w);
    o[4] = f2b(b.x); o[5] = f2b(b.y); o[6] = f2b(b.z); o[7] = f2b(b.w);
    return o;
}

// fp32-input gemm core (64x64 tile), reg-prefetch; same numerics as always.
__device__ __forceinline__ void gemm_core_f32(
    const float* __restrict__ A, int lda, const float* __restrict__ B, int ldb,
    int r0, int c0, int K, ushort_t (*as)[64], ushort_t (*bs)[64], f4 acc[2][2])
{
    const int t = threadIdx.x;
    const int wave = t >> 6, lane = t & 63;
    const int wm = (wave & 1) * 32, wn = (wave >> 1) * 32;
    const int fm = lane & 15, fq = lane >> 4;

    const int m1 = wave * 16 + (lane >> 3);
    const int m2 = m1 + 8;
    const int g1 = ((lane & 7) ^ (m1 & 7)) * 8;
    const int g2 = ((lane & 7) ^ (m2 & 7)) * 8;
    const int cl = (lane & 7) * 8;
    const int ra0 = wm + fm, ra1 = wm + 16 + fm;
    const int rb0 = wn + fm, rb1 = wn + 16 + fm;

    const float* pa1 = A + (size_t)(r0 + m1) * lda + g1;
    const float* pa2 = A + (size_t)(r0 + m2) * lda + g2;
    const float* pb1 = B + (size_t)(c0 + m1) * ldb + g1;
    const float* pb2 = B + (size_t)(c0 + m2) * ldb + g2;

    float4 aa0 = *(const float4*)(pa1);
    float4 aa1 = *(const float4*)(pa1 + 4);
    float4 ab0 = *(const float4*)(pa2);
    float4 ab1 = *(const float4*)(pa2 + 4);
    float4 ba0 = *(const float4*)(pb1);
    float4 ba1 = *(const float4*)(pb1 + 4);
    float4 bb0 = *(const float4*)(pb2);
    float4 bb1 = *(const float4*)(pb2 + 4);

    for (int k0 = 0; k0 < K; k0 += 64) {
        __syncthreads();
        *(us8*)&as[m1][cl] = cvt8(aa0, aa1);
        *(us8*)&as[m2][cl] = cvt8(ab0, ab1);
        *(us8*)&bs[m1][cl] = cvt8(ba0, ba1);
        *(us8*)&bs[m2][cl] = cvt8(bb0, bb1);
        __syncthreads();
        if (k0 + 64 < K) {
            aa0 = *(const float4*)(pa1 + k0 + 64);
            aa1 = *(const float4*)(pa1 + k0 + 68);
            ab0 = *(const float4*)(pa2 + k0 + 64);
            ab1 = *(const float4*)(pa2 + k0 + 68);
            ba0 = *(const float4*)(pb1 + k0 + 64);
            ba1 = *(const float4*)(pb1 + k0 + 68);
            bb0 = *(const float4*)(pb2 + k0 + 64);
            bb1 = *(const float4*)(pb2 + k0 + 68);
        }
        #pragma unroll
        for (int kk = 0; kk < 2; ++kk) {
            const int cc = kk * 4 + fq;
            const s8 a0 = *(const s8*)&as[ra0][(cc ^ (ra0 & 7)) * 8];
            const s8 a1 = *(const s8*)&as[ra1][(cc ^ (ra1 & 7)) * 8];
            const s8 b0 = *(const s8*)&bs[rb0][(cc ^ (rb0 & 7)) * 8];
            const s8 b1 = *(const s8*)&bs[rb1][(cc ^ (rb1 & 7)) * 8];
            acc[0][0] = __builtin_amdgcn_mfma_f32_16x16x32_bf16(a0, b0, acc[0][0], 0, 0, 0);
            acc[0][1] = __builtin_amdgcn_mfma_f32_16x16x32_bf16(a0, b1, acc[0][1], 0, 0, 0);
            acc[1][0] = __builtin_amdgcn_mfma_f32_16x16x32_bf16(a1, b0, acc[1][0], 0, 0, 0);
            acc[1][1] = __builtin_amdgcn_mfma_f32_16x16x32_bf16(a1, b1, acc[1][1], 0, 0, 0);
        }
    }
}

// ---------------------------------------------------------------------------
// K1 union (wih-cvt moved to attn; grid = exactly 1024 blocks = 1 round):
//  [0,256)      edge scan   [256,384) attn_proj
//  [384,1024)   gemm1 tiles: [msg0|msg1|gh] = x @ [Wm0;Wm1;whh]^T + bias
// ---------------------------------------------------------------------------
#define E_SC  256
#define E_AP  384
#define E_NB  1024

__global__ __launch_bounds__(256) void fused1_kernel(
    const float* __restrict__ x,
    const float* __restrict__ adj0, const float* __restrict__ adj1,
    const float* __restrict__ Wm0, const float* __restrict__ Wm1,
    const float* __restrict__ whh,
    const float* __restrict__ Wa0, const float* __restrict__ Wa1,
    const float* __restrict__ bm0, const float* __restrict__ bm1,
    const float* __restrict__ bhh,
    int* __restrict__ cnt, int* __restrict__ ej,
    float* __restrict__ acur, float* __restrict__ anb,
    ushort_t* __restrict__ msgb, float* __restrict__ gh)
{
    __shared__ char smem[16448];               // max(gemm 16384, attn_proj 16448)
    const int b = blockIdx.x, t = threadIdx.x;

    if (b < E_SC) {                            // ---- adj-only edge scan ----
        const int l = b & 1, chunk = b >> 1;
        const int i0 = chunk * 16;
        const float* adj = l ? adj1 : adj0;
        int* lcnt = (int*)smem;
        if (t < 16) lcnt[t] = 0;
        __syncthreads();
        const int rowLane = t >> 2, q = t & 3;
        for (int r0r = 0; r0r < NN; r0r += 512) {
            float4 a[8];
            #pragma unroll
            for (int it = 0; it < 8; ++it) {
                const int j = r0r + it * 64 + rowLane;
                a[it] = *(const float4*)(adj + (size_t)j * NN + i0 + q * 4);
            }
            #pragma unroll
            for (int it = 0; it < 8; ++it) {
                const int j = r0r + it * 64 + rowLane;
                const float av[4] = {a[it].x, a[it].y, a[it].z, a[it].w};
                #pragma unroll
                for (int u = 0; u < 4; ++u) {
                    if (av[u] != 0.f) {
                        const int li = q * 4 + u;
                        const int slot = atomicAdd(&lcnt[li], 1);
                        if (slot < ECAP)
                            ej[((size_t)l * NN + i0 + li) * ECAP + slot] = j;
                    }
                }
            }
        }
        __syncthreads();
        if (t < 16) cnt[l * NN + i0 + t] = min(lcnt[t], ECAP);
        return;
    }
    if (b < E_AP) {                            // ---- attn_proj ----
        float* sh = (float*)smem;              // [16][257]
        const int i0 = (b - E_SC) * 16;
        for (int rr = 0; rr < 16; ++rr)
            sh[rr * 257 + t] = x[(size_t)(i0 + rr) * DD + t];
        __syncthreads();
        const int r = t >> 4, idx = t & 15;
        const int l = idx >> 3, isnb = (idx >> 2) & 1, h = idx & 3;
        const float* wrow = (l ? Wa1 : Wa0) + h * (2 * DD) + isnb * DD;
        float acc = 0.f;
        for (int k = 0; k < DD; ++k) acc = fmaf(sh[r * 257 + k], wrow[k], acc);
        float* dst = isnb ? anb : acur;
        dst[((size_t)l * NN + i0 + r) * HH + h] = acc;
        return;
    }
    {                                          // ---- gemm1 tile (fp32 in) ----
        ushort_t (*as)[64] = (ushort_t(*)[64])smem;
        ushort_t (*bs)[64] = (ushort_t(*)[64])(smem + 8192);
        const int wave = t >> 6, lane = t & 63;
        const int wm = (wave & 1) * 32, wn = (wave >> 1) * 32;
        const int fm = lane & 15, fq = lane >> 4;
        const int idx = b - E_AP;
        const int c0 = (idx % 20) * 64, r0 = (idx / 20) * 64;
        const float* Bsrc = (c0 < 256) ? Wm0 + (size_t)c0 * DD
                          : (c0 < 512) ? Wm1 + (size_t)(c0 - 256) * DD
                                       : whh + (size_t)(c0 - 512) * DD;
        f4 acc[2][2] = {};
        gemm_core_f32(x, DD, Bsrc, DD, r0, 0, DD, as, bs, acc);
        // C/D layout (m89-verified): col = lane&15, row = (lane>>4)*4 + reg
        #pragma unroll
        for (int ni = 0; ni < 2; ++ni) {
            const int col = c0 + wn + ni * 16 + fm;
            const float bv = (col < 256) ? bm0[col]
                           : (col < 512) ? bm1[col - 256]
                                         : bhh[col - 512];
            #pragma unroll
            for (int mi = 0; mi < 2; ++mi) {
                #pragma unroll
                for (int r = 0; r < 4; ++r) {
                    const int row = r0 + wm + mi * 16 + fq * 4 + r;
                    const float v = acc[mi][ni][r] + bv;
                    if (col < 512) msgb[(size_t)row * 512 + col] = f2b(v);
                    else           gh[(size_t)row * 768 + col - 512] = v;
                }
            }
        }
    }
}

// ---------------------------------------------------------------------------
// K2 attn (R1 body): gather w per edge, edge-only softmax, aggregate bf16
// msg. PLUS: converts its 96-float slice of wih -> bf16 (issued first,
// overlaps with the latency-bound gather phase; gemm2 consumes wihb later).
// ---------------------------------------------------------------------------
__global__ __launch_bounds__(256) void attn_kernel(
    const int* __restrict__ cnt, const int* __restrict__ ej,
    const float* __restrict__ w0, const float* __restrict__ w1,
    const float* __restrict__ acur, const float* __restrict__ anb,
    const float* __restrict__ ba0, const float* __restrict__ ba1,
    const ushort_t* __restrict__ msgb, ushort_t* __restrict__ mcatb,
    const float* __restrict__ wih, ushort_t* __restrict__ wihb)
{
    const int i = blockIdx.x, l = blockIdx.y, t = threadIdx.x;
    __shared__ float es[HH][ECAP];
    __shared__ int ejs[ECAP];

    // wih -> bf16: 96 elems per block (4096 blocks x 96 = 768*512)
    {
        const int fb = i + (l << 11);
        if (t < 24) {
            const int id = fb * 96 + t * 4;
            const float4 v = *(const float4*)(wih + id);
            us4 o; o.x = f2b(v.x); o.y = f2b(v.y); o.z = f2b(v.z); o.w = f2b(v.w);
            *(us4*)(wihb + id) = o;
        }
    }

    const int ne = min(max(cnt[l * NN + i], 0), ECAP);
    const float* ba = l ? ba1 : ba0;
    const float* w  = l ? w1 : w0;
    const size_t ebase = ((size_t)l * NN + i) * ECAP;

    if (t < ne) {
        const int j = ej[ebase + t];
        const float wv = w[(size_t)j * NN + i];   // latency-parallel gather
        ejs[t] = j;
        const float4 av = *(const float4*)(anb + ((size_t)l * NN + j) * HH);
        const float sv[4] = {av.x, av.y, av.z, av.w};
        #pragma unroll
        for (int h = 0; h < HH; ++h) {
            float s = sv[h] + acur[((size_t)l * NN + i) * HH + h] + ba[h];
            s = (s > 0.f) ? s : 0.2f * s;           // leaky_relu(0.2)
            es[h][t] = s * wv;
        }
    }
    __syncthreads();
    {
        const int h = t >> 6, lane = t & 63;
        float s0 = (lane < ne) ? es[h][lane] : -1e30f;
        float s1 = (lane + 64 < ne) ? es[h][lane + 64] : -1e30f;
        float m = fmaxf(s0, s1);
        #pragma unroll
        for (int off = 32; off; off >>= 1) m = fmaxf(m, __shfl_xor(m, off));
        const float p0 = expf(s0 - m), p1 = expf(s1 - m);
        float sum = p0 + p1;
        #pragma unroll
        for (int off = 32; off; off >>= 1) sum += __shfl_xor(sum, off);
        const float inv = (ne > 0) ? 1.f / sum : 0.f;
        es[h][lane] = p0 * inv;
        if (lane + 64 < ECAP) es[h][lane + 64] = p1 * inv;
    }
    __syncthreads();
    const int h = t >> 6;
    const int off = l * DD + t;
    float acc = 0.f;
    int e = 0;
    for (; e + 8 <= ne; e += 8) {
        float v[8];
        #pragma unroll
        for (int u = 0; u < 8; ++u)
            v[u] = b2f(msgb[(size_t)ejs[e + u] * 512 + off]);
        #pragma unroll
        for (int u = 0; u < 8; ++u)
            acc = fmaf(es[h][e + u], v[u], acc);
    }
    for (; e < ne; ++e)
        acc = fmaf(es[h][e], b2f(msgb[(size_t)ejs[e] * 512 + off]), acc);
    mcatb[(size_t)i * (2 * DD) + off] = f2b(acc);
}

// ---------------------------------------------------------------------------
// K3: gemm2, BM=128 x BN=64 tile, K=512, double-buffered gl_lds staging.
// grid (12, 16) = 192 blocks. Wave w owns rows [w*32, w*32+32) x all 64
// cols: acc[2][4]. Same per-tile MFMA chunk order as before -> gi values
// bit-identical. LDS 48KB.
// ---------------------------------------------------------------------------
__global__ __launch_bounds__(256) void gemm2_kernel(
    const ushort_t* __restrict__ mcatb, const ushort_t* __restrict__ wihb,
    const float* __restrict__ bih, float* __restrict__ gi)
{
    __shared__ ushort_t as[256][64];           // 2 bufs x 128 rows
    __shared__ ushort_t bs[128][64];           // 2 bufs x 64 rows
    const int t = threadIdx.x;
    const int wave = t >> 6, lane = t & 63;
    const int wm = wave * 32;
    const int fm = lane & 15, fq = lane >> 4;
    const int c0 = blockIdx.x * 64, r0 = blockIdx.y * 128;

    const int lr = lane >> 3;                  // row within 8-row gl_lds group
    const int swz = ((lane & 7) ^ lr) * 8;     // pre-swizzled source chunk
    const ushort_t* gaA[4];
    const ushort_t* gaB[2];
    #pragma unroll
    for (int g = 0; g < 4; ++g)
        gaA[g] = mcatb + (size_t)(r0 + wm + g * 8 + lr) * 512 + swz;
    #pragma unroll
    for (int g = 0; g < 2; ++g)
        gaB[g] = wihb + (size_t)(c0 + wave * 16 + g * 8 + lr) * 512 + swz;

    f4 acc[2][4] = {};

    #pragma unroll
    for (int g = 0; g < 4; ++g) gl_lds16(gaA[g], &as[wm + g * 8][0]);
    #pragma unroll
    for (int g = 0; g < 2; ++g) gl_lds16(gaB[g], &bs[wave * 16 + g * 8][0]);
    __syncthreads();

    int abuf = 0, bbuf = 0;
    for (int k0 = 0; k0 < 512; k0 += 64) {
        const int na = abuf ^ 128, nb = bbuf ^ 64;
        if (k0 + 64 < 512) {
            #pragma unroll
            for (int g = 0; g < 4; ++g)
                gl_lds16(gaA[g] + k0 + 64, &as[na + wm + g * 8][0]);
            #pragma unroll
            for (int g = 0; g < 2; ++g)
                gl_lds16(gaB[g] + k0 + 64, &bs[nb + wave * 16 + g * 8][0]);
        }
        #pragma unroll
        for (int kk = 0; kk < 2; ++kk) {
            const int cc = kk * 4 + fq;
            const int ce = (cc ^ (fm & 7)) * 8;
            s8 af[2], bf[4];
            #pragma unroll
            for (int mi = 0; mi < 2; ++mi)
                af[mi] = *(const s8*)&as[abuf + wm + mi * 16 + fm][ce];
            #pragma unroll
            for (int ni = 0; ni < 4; ++ni)
                bf[ni] = *(const s8*)&bs[bbuf + ni * 16 + fm][ce];
            #pragma unroll
            for (int mi = 0; mi < 2; ++mi)
                #pragma unroll
                for (int ni = 0; ni < 4; ++ni)
                    acc[mi][ni] = __builtin_amdgcn_mfma_f32_16x16x32_bf16(
                        af[mi], bf[ni], acc[mi][ni], 0, 0, 0);
        }
        __syncthreads();
        abuf = na; bbuf = nb;
    }
    #pragma unroll
    for (int ni = 0; ni < 4; ++ni) {
        const int col = c0 + ni * 16 + fm;
        const float bv = bih[col];
        #pragma unroll
        for (int mi = 0; mi < 2; ++mi)
            #pragma unroll
            for (int r = 0; r < 4; ++r)
                gi[(size_t)(r0 + wm + mi * 16 + fq * 4 + r) * 768 + col] =
                    acc[mi][ni][r] + bv;
    }
}

// ---------------------------------------------------------------------------
// K4: GRU gates + LayerNorm. One row per wave, float4 I/O, shuffle-only
// reduction, zero barriers.
// ---------------------------------------------------------------------------
__global__ __launch_bounds__(256) void gates_ln(
    const float* __restrict__ gi, const float* __restrict__ gh, const float* __restrict__ x,
    const float* __restrict__ lng, const float* __restrict__ lnb, float* __restrict__ out)
{
    const int t = threadIdx.x;
    const int lane = t & 63, wv = t >> 6;
    const int row = blockIdx.x * 4 + wv;
    const size_t b768 = (size_t)row * 768;
    const int c = lane * 4;
    const f4 gir = *(const f4*)(gi + b768 + c);
    const f4 giz = *(const f4*)(gi + b768 + 256 + c);
    const f4 gin = *(const f4*)(gi + b768 + 512 + c);
    const f4 ghr = *(const f4*)(gh + b768 + c);
    const f4 ghz = *(const f4*)(gh + b768 + 256 + c);
    const f4 ghn = *(const f4*)(gh + b768 + 512 + c);
    const f4 xv  = *(const f4*)(x + (size_t)row * DD + c);
    f4 hv;
    float s1 = 0.f, s2 = 0.f;
    #pragma unroll
    for (int u = 0; u < 4; ++u) {
        const float rr = 1.f / (1.f + expf(-(gir[u] + ghr[u])));
        const float zz = 1.f / (1.f + expf(-(giz[u] + ghz[u])));
        const float nn = tanhf(gin[u] + rr * ghn[u]);
        const float h = (1.f - zz) * nn + zz * xv[u];
        hv[u] = h;
        s1 += h;
        s2 += h * h;
    }
    #pragma unroll
    for (int off = 32; off; off >>= 1) {
        s1 += __shfl_xor(s1, off);
        s2 += __shfl_xor(s2, off);
    }
    const float mu  = s1 * (1.f / DD);
    const float var = s2 * (1.f / DD) - mu * mu;
    const float inv = rsqrtf(var + 1e-5f);
    const f4 gv = *(const f4*)(lng + c);
    const f4 bv = *(const f4*)(lnb + c);
    f4 res;
    #pragma unroll
    for (int u = 0; u < 4; ++u)
        res[u] = (hv[u] - mu) * inv * gv[u] + bv[u];
    *(f4*)(out + (size_t)row * DD + c) = res;
}

extern "C" void kernel_launch(void* const* d_in, const int* in_sizes, int n_in,
                              void* d_out, int out_size, void* d_ws, size_t ws_size,
                              hipStream_t stream)
{
    const float* x    = (const float*)d_in[0];
    const float* adj0 = (const float*)d_in[1];
    const float* adj1 = (const float*)d_in[2];
    const float* w0   = (const float*)d_in[3];
    const float* w1   = (const float*)d_in[4];
    const float* Wm0  = (const float*)d_in[5];
    const float* bm0  = (const float*)d_in[6];
    const float* Wa0  = (const float*)d_in[7];
    const float* ba0  = (const float*)d_in[8];
    const float* Wm1  = (const float*)d_in[9];
    const float* bm1  = (const float*)d_in[10];
    const float* Wa1  = (const float*)d_in[11];
    const float* ba1  = (const float*)d_in[12];
    const float* wih  = (const float*)d_in[13];
    const float* whh  = (const float*)d_in[14];
    const float* bih  = (const float*)d_in[15];
    const float* bhh  = (const float*)d_in[16];
    const float* lng  = (const float*)d_in[17];
    const float* lnb  = (const float*)d_in[18];
    float* out = (float*)d_out;

    float* ws = (float*)d_ws;
    float* gh   = ws;            ws += (size_t)NN * 768;
    float* gi   = ws;            ws += (size_t)NN * 768;
    float* acur = ws;            ws += 2 * NN * HH;
    float* anb  = ws;            ws += 2 * NN * HH;
    int*   cnt  = (int*)ws;      ws += 2 * NN;
    int*   ej   = (int*)ws;      ws += 2 * NN * ECAP;
    ushort_t* wihb  = (ushort_t*)ws;  ws += (size_t)768 * 512 / 2;
    ushort_t* msgb  = (ushort_t*)ws;  ws += (size_t)NN * 512 / 2;
    ushort_t* mcatb = (ushort_t*)ws;  ws += (size_t)NN * 512 / 2;

    fused1_kernel<<<E_NB, 256, 0, stream>>>(
        x, adj0, adj1, Wm0, Wm1, whh, Wa0, Wa1, bm0, bm1, bhh,
        cnt, ej, acur, anb, msgb, gh);
    attn_kernel<<<dim3(NN, 2), 256, 0, stream>>>(
        cnt, ej, w0, w1, acur, anb, ba0, ba1, msgb, mcatb, wih, wihb);
    gemm2_kernel<<<dim3(12, 16), 256, 0, stream>>>(mcatb, wihb, bih, gi);
    gates_ln<<<NN / 4, 256, 0, stream>>>(gi, gh, x, lng, lnb, out);
}